// Round 1
// baseline (62.738 us; speedup 1.0000x reference)
//
#include <hip/hip_runtime.h>

// GeometryKernelAttention: nearest-neighbor multi-scale gather + weighted sum.
// B=1, NQ=20000, H=8, L=4, P=8, D=32, NUM_VALUE=19560.
// Reference output: (1, 20000, 256) f32, returned twice (concatenated in d_out).

#define GKA_NQ       20000
#define GKA_H        8
#define GKA_NV       19560
#define GKA_OUT_HALF 5120000   // 20000 * 256

__global__ __launch_bounds__(256) void gka_kernel(
    const float* __restrict__ value,   // [NV, 8, 32] (b=1)
    const float* __restrict__ sloc,    // [NQ, 8, 4, 8, 2]
    const float* __restrict__ awgt,    // [NQ, 8, 4, 8]
    float* __restrict__ out)           // [2, NQ, 256]
{
    const int tid  = threadIdx.x;
    const int lane = tid & 63;
    const int q    = blockIdx.x * 4 + (tid >> 6);  // one wave per query
    const int h    = lane >> 3;                    // 8 heads per wave
    const int sub  = lane & 7;                     // 8 lanes per (q,h)

    // ---- Phase A: this lane computes samples j = 4*sub .. 4*sub+3 ----
    // 4 consecutive samples always lie in the same level: lvl = sub >> 1.
    const int lvl = sub >> 1;
    const int Wi  = (lvl == 0) ? 160 : (lvl == 1) ? 80 : (lvl == 2) ? 40 : 20;
    const int Hi  = (lvl == 0) ? 92  : (lvl == 1) ? 46 : (lvl == 2) ? 23 : 12;
    const int ls  = (lvl == 0) ? 0   : (lvl == 1) ? 14720 : (lvl == 2) ? 18400 : 19320;
    const float Wf = (float)Wi;
    const float Hf = (float)Hi;

    const int qh = q * GKA_H + h;
    const float4* lp = (const float4*)(sloc + (size_t)qh * 64 + sub * 8);
    const float4 xy0 = lp[0];
    const float4 xy1 = lp[1];
    const float4 w4  = *(const float4*)(awgt + (size_t)qh * 32 + sub * 4);

    int   fl[4];
    float wk[4];
    {
        const float xs[4] = {xy0.x, xy0.z, xy1.x, xy1.z};
        const float ys[4] = {xy0.y, xy0.w, xy1.y, xy1.w};
        const float ws[4] = {w4.x, w4.y, w4.z, w4.w};
        #pragma unroll
        for (int k = 0; k < 4; ++k) {
            const int col = (int)floorf(xs[k] * Wf);
            const int row = (int)floorf(ys[k] * Hf);
            const bool valid = (col >= 0) & (col < Wi) & (row >= 0) & (row < Hi);
            int f = ls + row * Wi + col;
            f = min(max(f, 0), GKA_NV - 1);
            fl[k] = f;
            wk[k] = valid ? ws[k] : 0.0f;
        }
    }

    // ---- Phase B: broadcast (flat, w) within 8-lane group, gather+FMA ----
    float4 acc = make_float4(0.f, 0.f, 0.f, 0.f);
    const float* vbase = value + h * 32 + sub * 4;  // + flat*256 per sample
    const int gbase = lane & 56;                    // group base lane
    #pragma unroll
    for (int j = 0; j < 32; ++j) {
        const int src = gbase | (j >> 2);
        const int   f = __shfl(fl[j & 3], src, 64);
        const float w = __shfl(wk[j & 3], src, 64);
        const float4 v = *(const float4*)(vbase + (size_t)f * 256);
        acc.x = fmaf(w, v.x, acc.x);
        acc.y = fmaf(w, v.y, acc.y);
        acc.z = fmaf(w, v.z, acc.z);
        acc.w = fmaf(w, v.w, acc.w);
    }

    // ---- Write both tuple outputs (identical) ----
    float* o = out + (size_t)q * 256 + lane * 4;
    *(float4*)o = acc;
    *(float4*)(o + GKA_OUT_HALF) = acc;
}

extern "C" void kernel_launch(void* const* d_in, const int* in_sizes, int n_in,
                              void* d_out, int out_size, void* d_ws, size_t ws_size,
                              hipStream_t stream) {
    const float* value = (const float*)d_in[0];
    // d_in[1] = spatial_shapes, d_in[2] = level_start_index: compile-time constants.
    const float* sloc  = (const float*)d_in[3];
    const float* awgt  = (const float*)d_in[4];
    float* out = (float*)d_out;

    dim3 grid(GKA_NQ / 4);   // 5000 blocks, 4 queries per 256-thread block
    gka_kernel<<<grid, 256, 0, stream>>>(value, sloc, awgt, out);
}

// Round 2
// 44.503 us; speedup vs baseline: 1.4098x; 1.4098x over previous
//
#include <hip/hip_runtime.h>

// GeometryKernelAttention: nearest-neighbor multi-scale gather + weighted sum.
// B=1, NQ=20000, H=8, L=4, P=8, D=32, NUM_VALUE=19560.
// Output: (1, 20000, 256) f32, returned twice (concatenated in d_out).
//
// R2: head<->XCD affinity. Each block processes ONE head (2.45 MB slice of
// value -> fits 4 MiB per-XCD L2). blockIdx.x % 8 == head, exploiting the
// round-robin block->XCD dispatch so each XCD's L2 caches exactly its head.

#define GKA_NQ       20000
#define GKA_H        8
#define GKA_NV       19560
#define GKA_OUT_HALF 5120000   // 20000 * 256

__global__ __launch_bounds__(256) void gka_kernel(
    const float* __restrict__ value,   // [NV, 8, 32] (b=1)
    const float* __restrict__ sloc,    // [NQ, 8, 4, 8, 2]
    const float* __restrict__ awgt,    // [NQ, 8, 4, 8]
    float* __restrict__ out)           // [2, NQ, 256]
{
    const int tid  = threadIdx.x;
    const int lane = tid & 63;
    const int wave = tid >> 6;                 // 0..3
    const int h      = blockIdx.x & 7;         // head == XCD (round-robin dispatch)
    const int qchunk = blockIdx.x >> 3;
    const int qq   = lane >> 3;                // query within wave: 0..7
    const int sub  = lane & 7;                 // d-quad owner within (q,h)
    const int q    = qchunk * 32 + wave * 8 + qq;

    // ---- Phase A: this lane computes samples j = 4*sub .. 4*sub+3 ----
    // 4 consecutive samples always lie in the same level: lvl = sub >> 1.
    const int lvl = sub >> 1;
    const int Wi  = (lvl == 0) ? 160 : (lvl == 1) ? 80 : (lvl == 2) ? 40 : 20;
    const int Hi  = (lvl == 0) ? 92  : (lvl == 1) ? 46 : (lvl == 2) ? 23 : 12;
    const int ls  = (lvl == 0) ? 0   : (lvl == 1) ? 14720 : (lvl == 2) ? 18400 : 19320;
    const float Wf = (float)Wi;
    const float Hf = (float)Hi;

    const int qh = q * GKA_H + h;
    const float4* lp = (const float4*)(sloc + (size_t)qh * 64 + sub * 8);
    const float4 xy0 = lp[0];
    const float4 xy1 = lp[1];
    const float4 w4  = *(const float4*)(awgt + (size_t)qh * 32 + sub * 4);

    int   fl[4];
    float wk[4];
    {
        const float xs[4] = {xy0.x, xy0.z, xy1.x, xy1.z};
        const float ys[4] = {xy0.y, xy0.w, xy1.y, xy1.w};
        const float ws[4] = {w4.x, w4.y, w4.z, w4.w};
        #pragma unroll
        for (int k = 0; k < 4; ++k) {
            const int col = (int)floorf(xs[k] * Wf);
            const int row = (int)floorf(ys[k] * Hf);
            const bool valid = (col >= 0) & (col < Wi) & (row >= 0) & (row < Hi);
            int f = ls + row * Wi + col;
            f = min(max(f, 0), GKA_NV - 1);
            fl[k] = f;
            wk[k] = valid ? ws[k] : 0.0f;
        }
    }

    // ---- Phase B: broadcast (flat, w) within 8-lane group, gather+FMA ----
    float4 acc = make_float4(0.f, 0.f, 0.f, 0.f);
    const float* vbase = value + h * 32 + sub * 4;  // + flat*256 per sample
    const int gbase = lane & 56;                    // group base lane
    #pragma unroll
    for (int j = 0; j < 32; ++j) {
        const int src = gbase | (j >> 2);
        const int   f = __shfl(fl[j & 3], src, 64);
        const float w = __shfl(wk[j & 3], src, 64);
        const float4 v = *(const float4*)(vbase + (size_t)f * 256);
        acc.x = fmaf(w, v.x, acc.x);
        acc.y = fmaf(w, v.y, acc.y);
        acc.z = fmaf(w, v.z, acc.z);
        acc.w = fmaf(w, v.w, acc.w);
    }

    // ---- Write both tuple outputs (identical) ----
    float* o = out + (size_t)q * 256 + h * 32 + sub * 4;
    *(float4*)o = acc;
    *(float4*)(o + GKA_OUT_HALF) = acc;
}

extern "C" void kernel_launch(void* const* d_in, const int* in_sizes, int n_in,
                              void* d_out, int out_size, void* d_ws, size_t ws_size,
                              hipStream_t stream) {
    const float* value = (const float*)d_in[0];
    // d_in[1] = spatial_shapes, d_in[2] = level_start_index: compile-time constants.
    const float* sloc  = (const float*)d_in[3];
    const float* awgt  = (const float*)d_in[4];
    float* out = (float*)d_out;

    // 625 query-chunks x 8 heads; blockIdx % 8 == head -> XCD affinity.
    dim3 grid((GKA_NQ / 32) * GKA_H);
    gka_kernel<<<grid, 256, 0, stream>>>(value, sloc, awgt, out);
}